// Round 1
// baseline (534.689 us; speedup 1.0000x reference)
//
#include <hip/hip_runtime.h>
#include <math.h>

#define S 128
#define D 256
#define HID 64
#define ROWS 4
#define LN_EPS 1e-5f

__device__ __forceinline__ float gelu_exact(float x) {
    return 0.5f * x * (1.0f + erff(x * 0.70710678118654752440f));
}

// ---------------- Kernel A: per-batch segment sums (counts + coord sums) ----
__global__ __launch_bounds__(256) void seg_sum_kernel(
    const float* __restrict__ coords,   // [B,N,3]
    const int* __restrict__ labels,     // [B,N]
    int* __restrict__ cnt,              // [B*S]
    float* __restrict__ sums,           // [B*S*3]
    int N, int chunks_per_batch)
{
    __shared__ int   scnt[S];
    __shared__ float sx[S], sy[S], sz[S];
    int t = threadIdx.x;
    if (t < S) { scnt[t] = 0; sx[t] = 0.f; sy[t] = 0.f; sz[t] = 0.f; }
    __syncthreads();

    int b     = blockIdx.x / chunks_per_batch;
    int chunk = blockIdx.x % chunks_per_batch;
    int per   = (N + chunks_per_batch - 1) / chunks_per_batch;
    int start = chunk * per;
    int end   = min(start + per, N);

    for (int i = start + t; i < end; i += blockDim.x) {
        int idx = b * N + i;
        int lbl = labels[idx];
        float x = coords[idx * 3 + 0];
        float y = coords[idx * 3 + 1];
        float z = coords[idx * 3 + 2];
        atomicAdd(&scnt[lbl], 1);
        atomicAdd(&sx[lbl], x);
        atomicAdd(&sy[lbl], y);
        atomicAdd(&sz[lbl], z);
    }
    __syncthreads();
    if (t < S && scnt[t] != 0) {
        atomicAdd(&cnt[b * S + t], scnt[t]);
        atomicAdd(&sums[(b * S + t) * 3 + 0], sx[t]);
        atomicAdd(&sums[(b * S + t) * 3 + 1], sy[t]);
        atomicAdd(&sums[(b * S + t) * 3 + 2], sz[t]);
    }
}

// ---------------- Kernel B1: centers -> rel features (one block per batch) --
__global__ __launch_bounds__(S) void rel_kernel(
    const int* __restrict__ cnt,
    const float* __restrict__ sums,
    float* __restrict__ rel,    // [B*S*4]
    float* __restrict__ scale)  // [B*S]
{
    __shared__ float cx[S], cy[S], cz[S], vm[S];
    int b = blockIdx.x;
    int s = threadIdx.x;  // 128 threads

    int c = cnt[b * S + s];
    float dc = fmaxf((float)c, 1.0f);
    float x = sums[(b * S + s) * 3 + 0] / dc;
    float y = sums[(b * S + s) * 3 + 1] / dc;
    float z = sums[(b * S + s) * 3 + 2] / dc;
    float v = (c >= 2) ? 1.0f : 0.0f;
    cx[s] = x; cy[s] = y; cz[s] = z; vm[s] = v;
    __syncthreads();

    float nv = 0.f, sum_d = 0.f, frac = 0.f, min_d = INFINITY;
    for (int j = 0; j < S; j++) {
        float dx = x - cx[j], dy = y - cy[j], dz = z - cz[j];
        float d2 = dx * dx + dy * dy + dz * dz;
        float dist = (d2 > 0.0f) ? sqrtf(d2) : 0.0f;  // matches sqrt(where(d2>0,d2,1))*(d2>0)
        float vj = vm[j];
        nv    += vj;
        sum_d += dist * vj;
        if (vj > 0.0f) min_d = fminf(min_d, dist);
        frac  += (z > cz[j]) ? vj : 0.0f;
    }
    float denom = fmaxf(nv, 1.0f);
    rel[(b * S + s) * 4 + 0] = sum_d / denom;
    rel[(b * S + s) * 4 + 1] = min_d;
    rel[(b * S + s) * 4 + 2] = z;
    rel[(b * S + s) * 4 + 3] = frac / denom;
    scale[b * S + s] = v * ((nv >= 2.0f) ? 1.0f : 0.0f);
}

// ---------------- Kernel B2: MLP chain, ROWS superpoints per block ----------
__global__ __launch_bounds__(D) void mlp_kernel(
    const float* __restrict__ rel, const float* __restrict__ scale,
    const float* __restrict__ W1, const float* __restrict__ b1,
    const float* __restrict__ W2, const float* __restrict__ b2,
    const float* __restrict__ W3, const float* __restrict__ b3,
    const float* __restrict__ lng, const float* __restrict__ lnb,
    const float* __restrict__ W4, const float* __restrict__ b4,
    float* __restrict__ a_table)   // [B*S*D]
{
    __shared__ float relS[ROWS][4];
    __shared__ float h1[ROWS][HID];
    __shared__ float h2[ROWS][D];
    __shared__ float red[4][ROWS][2];

    int t = threadIdx.x;          // 256 threads, one output column each
    int base = blockIdx.x * ROWS; // global row index into [B*S]

    if (t < ROWS * 4) relS[t >> 2][t & 3] = rel[base * 4 + t];
    __syncthreads();

    if (t < HID) {
        for (int r = 0; r < ROWS; r++) {
            float acc = b1[t];
            #pragma unroll
            for (int k = 0; k < 4; k++) acc += relS[r][k] * W1[k * HID + t];
            h1[r][t] = gelu_exact(acc);
        }
    }
    __syncthreads();

    { // h2 = h1 @ W2 + b2
        float acc[ROWS];
        #pragma unroll
        for (int r = 0; r < ROWS; r++) acc[r] = b2[t];
        for (int k = 0; k < HID; k++) {
            float w = W2[k * D + t];
            #pragma unroll
            for (int r = 0; r < ROWS; r++) acc[r] += h1[r][k] * w;
        }
        #pragma unroll
        for (int r = 0; r < ROWS; r++) h2[r][t] = acc[r];
    }
    __syncthreads();

    // a = h2 @ W3 + b3
    float a[ROWS];
    #pragma unroll
    for (int r = 0; r < ROWS; r++) a[r] = b3[t];
    for (int k = 0; k < D; k++) {
        float w = W3[k * D + t];
        #pragma unroll
        for (int r = 0; r < ROWS; r++) a[r] += h2[r][k] * w;
    }

    // LayerNorm stats via wave shuffles (wave = 64 lanes on CDNA)
    int wave = t >> 6, lane = t & 63;
    #pragma unroll
    for (int r = 0; r < ROWS; r++) {
        float s1 = a[r], s2 = a[r] * a[r];
        for (int off = 32; off > 0; off >>= 1) {
            s1 += __shfl_down(s1, off);
            s2 += __shfl_down(s2, off);
        }
        if (lane == 0) { red[wave][r][0] = s1; red[wave][r][1] = s2; }
    }
    __syncthreads();

    float xg[ROWS];
    float g = lng[t], bb = lnb[t];
    #pragma unroll
    for (int r = 0; r < ROWS; r++) {
        float s1 = red[0][r][0] + red[1][r][0] + red[2][r][0] + red[3][r][0];
        float s2 = red[0][r][1] + red[1][r][1] + red[2][r][1] + red[3][r][1];
        float mu  = s1 / (float)D;
        float var = s2 / (float)D - mu * mu;
        float ln = (a[r] - mu) * rsqrtf(var + LN_EPS) * g + bb;
        xg[r] = gelu_exact(ln);
    }
    __syncthreads();           // all reads of h2 are done; safe to overwrite
    #pragma unroll
    for (int r = 0; r < ROWS; r++) h2[r][t] = xg[r];
    __syncthreads();

    // out = x @ W4 + b4, then mask
    float o[ROWS];
    #pragma unroll
    for (int r = 0; r < ROWS; r++) o[r] = b4[t];
    for (int k = 0; k < D; k++) {
        float w = W4[k * D + t];
        #pragma unroll
        for (int r = 0; r < ROWS; r++) o[r] += h2[r][k] * w;
    }
    #pragma unroll
    for (int r = 0; r < ROWS; r++) {
        a_table[(size_t)(base + r) * D + t] = o[r] * scale[base + r];
    }
}

// ---------------- Kernel C: gather rows, one wave per output row ------------
__global__ __launch_bounds__(256) void gather_kernel(
    const int* __restrict__ labels,        // [B*N]
    const float4* __restrict__ a_table,    // [B*S*64] float4
    float4* __restrict__ out,              // [B*N*64] float4
    int N, int total_rows)
{
    int row  = blockIdx.x * 4 + (threadIdx.x >> 6);
    int lane = threadIdx.x & 63;
    if (row >= total_rows) return;
    int b   = row / N;
    int lbl = labels[row];
    out[(size_t)row * 64 + lane] = a_table[(size_t)(b * S + lbl) * 64 + lane];
}

extern "C" void kernel_launch(void* const* d_in, const int* in_sizes, int n_in,
                              void* d_out, int out_size, void* d_ws, size_t ws_size,
                              hipStream_t stream) {
    const float* coords = (const float*)d_in[0];
    // d_in[1] = features : UNUSED by the reference output
    const int*   labels = (const int*)d_in[2];
    // d_in[3] = num_superpoints (scalar) : S hard-coded = 128
    const float* W1 = (const float*)d_in[4];
    const float* b1 = (const float*)d_in[5];
    const float* W2 = (const float*)d_in[6];
    const float* b2 = (const float*)d_in[7];
    const float* W3 = (const float*)d_in[8];
    const float* b3 = (const float*)d_in[9];
    const float* lng = (const float*)d_in[10];
    const float* lnb = (const float*)d_in[11];
    const float* W4 = (const float*)d_in[12];
    const float* b4 = (const float*)d_in[13];

    const int B = 8;
    const int total_rows = in_sizes[2];   // B*N = 320000
    const int N = total_rows / B;         // 40000

    // workspace layout (16B-aligned pieces)
    char* ws = (char*)d_ws;
    int*   cnt     = (int*)(ws + 0);                 // B*S ints        (4 KB)
    float* sums    = (float*)(ws + 4096);            // B*S*3 floats    (12 KB)
    float* rel     = (float*)(ws + 16384);           // B*S*4 floats    (16 KB)
    float* scale   = (float*)(ws + 32768);           // B*S floats      (4 KB)
    float* a_table = (float*)(ws + 36864);           // B*S*D floats    (1 MB)

    // zero the accumulators (ws is poisoned 0xAA before every call)
    hipMemsetAsync(ws, 0, 16384, stream);

    const int chunks = 32;
    seg_sum_kernel<<<B * chunks, 256, 0, stream>>>(coords, labels, cnt, sums, N, chunks);
    rel_kernel<<<B, S, 0, stream>>>(cnt, sums, rel, scale);
    mlp_kernel<<<(B * S) / ROWS, D, 0, stream>>>(rel, scale, W1, b1, W2, b2, W3, b3,
                                                 lng, lnb, W4, b4, a_table);
    gather_kernel<<<(total_rows + 3) / 4, 256, 0, stream>>>(
        labels, (const float4*)a_table, (float4*)d_out, N, total_rows);
}

// Round 2
// 521.484 us; speedup vs baseline: 1.0253x; 1.0253x over previous
//
#include <hip/hip_runtime.h>
#include <math.h>

#define S 128
#define D 256
#define HID 64
#define ROWS 4
#define CHUNKS 32
#define LN_EPS 1e-5f

typedef float v4 __attribute__((ext_vector_type(4)));

__device__ __forceinline__ float gelu_exact(float x) {
    return 0.5f * x * (1.0f + erff(x * 0.70710678118654752440f));
}

// ---------------- Kernel A: per-(batch,chunk) partial segment sums ----------
// Each block owns its partial slice -> no global atomics, no zero-init needed.
__global__ __launch_bounds__(256) void seg_partial_kernel(
    const float* __restrict__ coords,   // [B,N,3]
    const int* __restrict__ labels,     // [B,N]
    float4* __restrict__ partial,       // [B*CHUNKS*S] {cnt,sx,sy,sz}
    int N)
{
    __shared__ int   scnt[S];
    __shared__ float sx[S], sy[S], sz[S];
    int t = threadIdx.x;
    if (t < S) { scnt[t] = 0; sx[t] = 0.f; sy[t] = 0.f; sz[t] = 0.f; }
    __syncthreads();

    int b     = blockIdx.x / CHUNKS;
    int chunk = blockIdx.x % CHUNKS;
    int per   = (N + CHUNKS - 1) / CHUNKS;
    int start = chunk * per;
    int end   = min(start + per, N);

    for (int i = start + t; i < end; i += blockDim.x) {
        int idx = b * N + i;
        int lbl = labels[idx];
        float x = coords[idx * 3 + 0];
        float y = coords[idx * 3 + 1];
        float z = coords[idx * 3 + 2];
        atomicAdd(&scnt[lbl], 1);
        atomicAdd(&sx[lbl], x);
        atomicAdd(&sy[lbl], y);
        atomicAdd(&sz[lbl], z);
    }
    __syncthreads();
    if (t < S) {
        float4 p;
        p.x = (float)scnt[t]; p.y = sx[t]; p.z = sy[t]; p.w = sz[t];
        partial[(size_t)blockIdx.x * S + t] = p;
    }
}

// ---------------- Kernel B: fused centers -> rel -> MLP ---------------------
// One block per 4 superpoints (256 blocks of 256 threads).
__global__ __launch_bounds__(256) void fused_mlp_kernel(
    const float4* __restrict__ partial,
    const float* __restrict__ W1, const float* __restrict__ b1,
    const float* __restrict__ W2, const float* __restrict__ b2,
    const float* __restrict__ W3, const float* __restrict__ b3,
    const float* __restrict__ lng, const float* __restrict__ lnb,
    const float* __restrict__ W4, const float* __restrict__ b4,
    float* __restrict__ a_table)   // [B*S*D]
{
    __shared__ float cx[S], cy[S], cz[S], vm[S];
    __shared__ float relS[ROWS][4];
    __shared__ float scaleS[ROWS];
    __shared__ float h1[ROWS][HID];
    __shared__ float h2[ROWS][D];
    __shared__ float red[4][ROWS][2];

    int t = threadIdx.x;
    int b = blockIdx.x >> 5;                 // 32 blocks per batch
    int base_seg = (blockIdx.x & 31) * ROWS;
    int base_row = b * S + base_seg;

    // Stage A: reduce 32 chunk partials -> centers
    if (t < S) {
        float4 acc = {0.f, 0.f, 0.f, 0.f};
        for (int c = 0; c < CHUNKS; c++) {
            float4 p = partial[(size_t)(b * CHUNKS + c) * S + t];
            acc.x += p.x; acc.y += p.y; acc.z += p.z; acc.w += p.w;
        }
        float dc = fmaxf(acc.x, 1.0f);
        cx[t] = acc.y / dc;
        cy[t] = acc.z / dc;
        cz[t] = acc.w / dc;
        vm[t] = (acc.x >= 2.0f) ? 1.0f : 0.0f;
    }
    __syncthreads();

    // Stage B: wave w computes rel features for superpoint base_seg+w
    int wv = t >> 6, lane = t & 63;
    {
        int sg = base_seg + wv;
        float x = cx[sg], y = cy[sg], z = cz[sg];
        float nv = 0.f, sum_d = 0.f, frac = 0.f, min_d = INFINITY;
        for (int j = lane; j < S; j += 64) {
            float dx = x - cx[j], dy = y - cy[j], dz = z - cz[j];
            float d2 = dx * dx + dy * dy + dz * dz;
            float dist = (d2 > 0.0f) ? sqrtf(d2) : 0.0f;
            float vj = vm[j];
            nv    += vj;
            sum_d += dist * vj;
            if (vj > 0.0f) min_d = fminf(min_d, dist);
            frac  += (z > cz[j]) ? vj : 0.0f;
        }
        for (int off = 32; off > 0; off >>= 1) {
            nv    += __shfl_down(nv, off);
            sum_d += __shfl_down(sum_d, off);
            frac  += __shfl_down(frac, off);
            min_d  = fminf(min_d, __shfl_down(min_d, off));
        }
        if (lane == 0) {
            float denom = fmaxf(nv, 1.0f);
            relS[wv][0] = sum_d / denom;
            relS[wv][1] = min_d;
            relS[wv][2] = z;
            relS[wv][3] = frac / denom;
            scaleS[wv]  = vm[sg] * ((nv >= 2.0f) ? 1.0f : 0.0f);
        }
    }
    __syncthreads();

    // Stage C: MLP chain, one output column per thread
    if (t < HID) {
        for (int r = 0; r < ROWS; r++) {
            float acc = b1[t];
            #pragma unroll
            for (int k = 0; k < 4; k++) acc += relS[r][k] * W1[k * HID + t];
            h1[r][t] = gelu_exact(acc);
        }
    }
    __syncthreads();

    { // h2 = h1 @ W2 + b2
        float acc[ROWS];
        #pragma unroll
        for (int r = 0; r < ROWS; r++) acc[r] = b2[t];
        for (int k = 0; k < HID; k++) {
            float w = W2[k * D + t];
            #pragma unroll
            for (int r = 0; r < ROWS; r++) acc[r] += h1[r][k] * w;
        }
        #pragma unroll
        for (int r = 0; r < ROWS; r++) h2[r][t] = acc[r];
    }
    __syncthreads();

    // a = h2 @ W3 + b3
    float a[ROWS];
    #pragma unroll
    for (int r = 0; r < ROWS; r++) a[r] = b3[t];
    for (int k = 0; k < D; k++) {
        float w = W3[k * D + t];
        #pragma unroll
        for (int r = 0; r < ROWS; r++) a[r] += h2[r][k] * w;
    }

    // LayerNorm stats via wave shuffles
    #pragma unroll
    for (int r = 0; r < ROWS; r++) {
        float s1 = a[r], s2 = a[r] * a[r];
        for (int off = 32; off > 0; off >>= 1) {
            s1 += __shfl_down(s1, off);
            s2 += __shfl_down(s2, off);
        }
        if (lane == 0) { red[wv][r][0] = s1; red[wv][r][1] = s2; }
    }
    __syncthreads();

    float g = lng[t], bb = lnb[t];
    float xg[ROWS];
    #pragma unroll
    for (int r = 0; r < ROWS; r++) {
        float s1 = red[0][r][0] + red[1][r][0] + red[2][r][0] + red[3][r][0];
        float s2 = red[0][r][1] + red[1][r][1] + red[2][r][1] + red[3][r][1];
        float mu  = s1 / (float)D;
        float var = s2 / (float)D - mu * mu;
        float ln = (a[r] - mu) * rsqrtf(var + LN_EPS) * g + bb;
        xg[r] = gelu_exact(ln);
    }
    __syncthreads();
    #pragma unroll
    for (int r = 0; r < ROWS; r++) h2[r][t] = xg[r];
    __syncthreads();

    float o[ROWS];
    #pragma unroll
    for (int r = 0; r < ROWS; r++) o[r] = b4[t];
    for (int k = 0; k < D; k++) {
        float w = W4[k * D + t];
        #pragma unroll
        for (int r = 0; r < ROWS; r++) o[r] += h2[r][k] * w;
    }
    #pragma unroll
    for (int r = 0; r < ROWS; r++) {
        a_table[(size_t)(base_row + r) * D + t] = o[r] * scaleS[r];
    }
}

// ---------------- Kernel C: grid-stride gather, nontemporal stores ----------
__global__ __launch_bounds__(256) void gather_kernel(
    const int* __restrict__ labels,     // [B*N]
    const v4* __restrict__ a_table,     // [B*S*64] float4
    v4* __restrict__ out,               // [B*N*64] float4
    int N, int M)                       // M = B*N*64
{
    int stride  = gridDim.x * blockDim.x;     // multiple of 64
    int rowStep = stride >> 6;
    int i    = blockIdx.x * blockDim.x + threadIdx.x;
    int row  = i >> 6;                        // wave-uniform
    int lane = i & 63;                        // constant across iterations
    int b    = row / N;                       // one divide, then incremental
    for (; i < M; i += stride, row += rowStep) {
        while (row >= (b + 1) * N) b++;       // wave-uniform, rare
        int lbl = labels[row];                // broadcast within wave
        v4 val = a_table[(size_t)((b << 7) + lbl) * 64 + lane];
        __builtin_nontemporal_store(val, &out[i]);
    }
}

extern "C" void kernel_launch(void* const* d_in, const int* in_sizes, int n_in,
                              void* d_out, int out_size, void* d_ws, size_t ws_size,
                              hipStream_t stream) {
    const float* coords = (const float*)d_in[0];
    // d_in[1] = features : UNUSED by the reference output
    const int*   labels = (const int*)d_in[2];
    // d_in[3] = num_superpoints (scalar) : S hard-coded = 128
    const float* W1 = (const float*)d_in[4];
    const float* b1 = (const float*)d_in[5];
    const float* W2 = (const float*)d_in[6];
    const float* b2 = (const float*)d_in[7];
    const float* W3 = (const float*)d_in[8];
    const float* b3 = (const float*)d_in[9];
    const float* lng = (const float*)d_in[10];
    const float* lnb = (const float*)d_in[11];
    const float* W4 = (const float*)d_in[12];
    const float* b4 = (const float*)d_in[13];

    const int B = 8;
    const int total_rows = in_sizes[2];   // B*N = 320000
    const int N = total_rows / B;         // 40000

    // workspace layout
    char* ws = (char*)d_ws;
    float4* partial = (float4*)(ws + 0);           // B*CHUNKS*S*16 = 512 KB (fully overwritten)
    float*  a_table = (float*)(ws + 524288);       // B*S*D*4 = 1 MB (fully overwritten)

    seg_partial_kernel<<<B * CHUNKS, 256, 0, stream>>>(coords, labels, partial, N);
    fused_mlp_kernel<<<(B * S) / ROWS, 256, 0, stream>>>(partial, W1, b1, W2, b2, W3, b3,
                                                         lng, lnb, W4, b4, a_table);
    int M = total_rows * (D / 4);
    gather_kernel<<<2048, 256, 0, stream>>>(labels, (const v4*)a_table, (v4*)d_out, N, M);
}